// Round 4
// baseline (157.610 us; speedup 1.0000x reference)
//
#include <hip/hip_runtime.h>
#include <hip/hip_bf16.h>
#include <cstdint>
#include <cstddef>
#include <math.h>

// Problem constants (reference: B=4096, D=256, T=0.5)
#define BSZ   4096
#define NROW  8192          // 2*B
#define DIM   256
#define INV_T 2.0f
#define EPS_N 1e-8f
#define CE    2.8853900817779268f   // INV_T * log2(e): e^(2x) = 2^(CE*x)

typedef __attribute__((ext_vector_type(8))) short bf16x8;   // 8 bf16 = 4 VGPRs
typedef __attribute__((ext_vector_type(4))) float f32x4;

__device__ __forceinline__ unsigned short f2bf(float x) {
    __hip_bfloat16 h = __float2bfloat16(x);
    return __builtin_bit_cast(unsigned short, h);
}
__device__ __forceinline__ float bf2f(unsigned short u) {
    __hip_bfloat16 h = __builtin_bit_cast(__hip_bfloat16, u);
    return __bfloat162float(h);
}

// ---------------------------------------------------------------------------
// Kernel 1: row-normalize concat(z1,z2) -> bf16 zn. Also writes the exact
// post-rounding diagonal term sii[row] = sum(bf16(zn)^2) (used by finalize to
// subtract exp(2*sim_ii) from the diag-inclusive rowsum) and zeroes rowsum.
__global__ __launch_bounds__(256)
void nt_normalize(const float* __restrict__ z1,
                  const float* __restrict__ z2,
                  __hip_bfloat16* __restrict__ zn,
                  float* __restrict__ rowsum,
                  float* __restrict__ sii) {
    const int wave = threadIdx.x >> 6;
    const int lane = threadIdx.x & 63;
    const int row  = blockIdx.x * 4 + wave;
    const float* src = (row < BSZ) ? (z1 + (size_t)row * DIM)
                                   : (z2 + (size_t)(row - BSZ) * DIM);
    const float4 v = ((const float4*)src)[lane];
    float ss = v.x * v.x + v.y * v.y + v.z * v.z + v.w * v.w;
    #pragma unroll
    for (int off = 32; off; off >>= 1) ss += __shfl_xor(ss, off);
    const float rinv = 1.0f / fmaxf(sqrtf(ss), EPS_N);  // torch eps clamp
    ushort4 o;
    o.x = f2bf(v.x * rinv);
    o.y = f2bf(v.y * rinv);
    o.z = f2bf(v.z * rinv);
    o.w = f2bf(v.w * rinv);
    ((ushort4*)(zn + (size_t)row * DIM))[lane] = o;
    // exact bf16-rounded sum of squares for this row
    float bx = bf2f(o.x), by = bf2f(o.y), bz = bf2f(o.z), bw = bf2f(o.w);
    float s2 = bx * bx + by * by + bz * bz + bw * bw;
    #pragma unroll
    for (int off = 32; off; off >>= 1) s2 += __shfl_xor(s2, off);
    if (lane == 0) { sii[row] = s2; rowsum[row] = 0.0f; }
}

// ---------------------------------------------------------------------------
// Kernel 2: Zn·Znᵀ upper triangle, NO LDS: the whole Zn is 4 MB = L2-resident,
// so fragments load straight from global (L2 hit ~200cyc, hidden by 2-deep
// register prefetch + ~12 waves/CU). No barriers anywhere. Rowsum includes the
// diagonal (finalize subtracts it); positives captured wave-uniformly in the
// 64 blocks on the bj==bi+32 strip.
__global__ __launch_bounds__(256)
void nt_gram(const __hip_bfloat16* __restrict__ zn,
             float* __restrict__ rowsum,
             float* __restrict__ pos) {
    // Triangular decode: S(bi) = 64*bi - bi*(bi-1)/2 tiles before row bi.
    const int l = blockIdx.x;
    int bi = (int)((129.0 - sqrt(16641.0 - 8.0 * (double)l)) * 0.5);
    while (64 * (bi + 1) - (bi + 1) * bi / 2 <= l) ++bi;
    while (64 * bi - bi * (bi - 1) / 2 > l) --bi;
    const int bj = bi + (l - (64 * bi - bi * (bi - 1) / 2));

    const int lane = threadIdx.x & 63;
    const int wave = threadIdx.x >> 6;
    const int wrow = (wave >> 1) * 64;
    const int wcol = (wave & 1) * 64;
    const int q    = lane >> 4;      // quad: A/B frag k-offset = q*8
    const int r16  = lane & 15;      // frag row/col within 16

    // A-frag (mi,ks): row bi*128+wrow+mi*16+r16, cols ks*32 + q*8 .. +8
    const __hip_bfloat16* Arow = zn + (size_t)(bi * 128 + wrow + r16) * DIM + q * 8;
    const __hip_bfloat16* Brow = zn + (size_t)(bj * 128 + wcol + r16) * DIM + q * 8;

    f32x4 acc[4][4] = {};
    bf16x8 a[2][4], b[2][4];

    #pragma unroll
    for (int mi = 0; mi < 4; ++mi) {
        a[0][mi] = *(const bf16x8*)(Arow + (size_t)mi * 16 * DIM);
        b[0][mi] = *(const bf16x8*)(Brow + (size_t)mi * 16 * DIM);
    }
    #pragma unroll
    for (int ks = 0; ks < 8; ++ks) {           // K = 8 * 32 = 256
        const int cur = ks & 1, nxt = cur ^ 1;
        if (ks < 7) {
            const __hip_bfloat16* An = Arow + (ks + 1) * 32;
            const __hip_bfloat16* Bn = Brow + (ks + 1) * 32;
            #pragma unroll
            for (int mi = 0; mi < 4; ++mi) {
                a[nxt][mi] = *(const bf16x8*)(An + (size_t)mi * 16 * DIM);
                b[nxt][mi] = *(const bf16x8*)(Bn + (size_t)mi * 16 * DIM);
            }
        }
        #pragma unroll
        for (int mi = 0; mi < 4; ++mi)
            #pragma unroll
            for (int ni = 0; ni < 4; ++ni)
                acc[mi][ni] = __builtin_amdgcn_mfma_f32_16x16x32_bf16(
                    a[cur][mi], b[cur][ni], acc[mi][ni], 0, 0, 0);
    }

    // Epilogue. C/D layout: col=lane&15, row=(lane>>4)*4+reg (m89-verified).
    // Pure exp+accumulate: no per-element compares.
    const int c = lane & 15;
    float colp[4] = {0.f, 0.f, 0.f, 0.f};

    #pragma unroll
    for (int mi = 0; mi < 4; ++mi) {
        #pragma unroll
        for (int r = 0; r < 4; ++r) {
            float s = 0.f;
            #pragma unroll
            for (int ni = 0; ni < 4; ++ni) {
                const float e = exp2f(acc[mi][ni][r] * CE);
                s += e;
                colp[ni] += e;
            }
            s += __shfl_xor(s, 1);
            s += __shfl_xor(s, 2);
            s += __shfl_xor(s, 4);
            s += __shfl_xor(s, 8);
            if (c == 0) {
                const int grow = bi * 128 + wrow + mi * 16 + q * 4 + r;
                atomicAdd(&rowsum[grow], s);
            }
        }
    }
    // Column sums feed the bj strip (symmetry); skip on diagonal tiles.
    if (bi != bj) {
        #pragma unroll
        for (int ni = 0; ni < 4; ++ni) {
            float cs = colp[ni];
            cs += __shfl_xor(cs, 16);
            cs += __shfl_xor(cs, 32);
            if (q == 0) atomicAdd(&rowsum[bj * 128 + wcol + ni * 16 + c], cs);
        }
    }
    // Positive pairs: global diag offset +BSZ = 32 tile-strips; local diagonal
    // lives in the wrow==wcol waves. Wave-uniform branch, 64 blocks only.
    if (bj == bi + 32 && wrow == wcol) {
        #pragma unroll
        for (int mi = 0; mi < 4; ++mi)
            #pragma unroll
            for (int r = 0; r < 4; ++r)
                if (c == q * 4 + r) {
                    const int grow = bi * 128 + wrow + mi * 16 + q * 4 + r;
                    const float val = acc[mi][mi][r];
                    pos[grow] = val;
                    pos[grow + BSZ] = val;
                }
    }
}

// ---------------------------------------------------------------------------
// Kernel 3: single block; subtract diagonal, add positive, reduce, write out.
__global__ __launch_bounds__(1024)
void nt_finalize(const float* __restrict__ rowsum,
                 const float* __restrict__ pos,
                 const float* __restrict__ sii,
                 float* __restrict__ out) {
    float v = 0.f;
    for (int i = threadIdx.x; i < NROW; i += 1024) {
        const float pl  = pos[i] * INV_T;
        const float neg = rowsum[i] - exp2f(sii[i] * CE);  // drop diagonal
        v += logf(__expf(pl) + neg) - pl;
    }
    #pragma unroll
    for (int off = 32; off; off >>= 1) v += __shfl_xor(v, off);
    __shared__ float red[16];
    if ((threadIdx.x & 63) == 0) red[threadIdx.x >> 6] = v;
    __syncthreads();
    if (threadIdx.x == 0) {
        float s = 0.f;
        #pragma unroll
        for (int w = 0; w < 16; ++w) s += red[w];
        out[0] = s * (1.0f / NROW);
    }
}

// ---------------------------------------------------------------------------
extern "C" void kernel_launch(void* const* d_in, const int* in_sizes, int n_in,
                              void* d_out, int out_size, void* d_ws, size_t ws_size,
                              hipStream_t stream) {
    const float* z1 = (const float*)d_in[0];
    const float* z2 = (const float*)d_in[1];
    float* out = (float*)d_out;

    __hip_bfloat16* zn = (__hip_bfloat16*)d_ws;                       // 4 MB
    float* rowsum = (float*)((char*)d_ws + (size_t)NROW * DIM * 2);   // 32 KB
    float* pos    = rowsum + NROW;                                    // 32 KB (fully written by gram)
    float* sii    = pos + NROW;                                       // 32 KB

    nt_normalize<<<NROW / 4, 256, 0, stream>>>(z1, z2, zn, rowsum, sii);
    nt_gram<<<2080, 256, 0, stream>>>(zn, rowsum, pos);
    nt_finalize<<<1, 1024, 0, stream>>>(rowsum, pos, sii, out);
}